// Round 14
// baseline (1072.911 us; speedup 1.0000x reference)
//
#include <hip/hip_runtime.h>
#include <stdint.h>

// GGNN round 28: transform-first. r27 (factored gi) banked 1041us. Next
// algebra step: materialize z_t = x @ msg_W[t]^T per node (dense GEMM,
// k_ztrans ~17us) so the gather sums PRE-TRANSFORMED rows:
//  - k_gather1: no 3-bin branching (type baked into pay offset
//    (et*N+src)*256), single v8hf acc, write 76.8->25.6MB. z lives in the
//    same L3 tier xb did (neither fits 4MB XCD L2) -> same random-read
//    throughput. 44 -> ~34us.
//  - k_mega2t = mega2s minus stage1 (-24 MFMA/wave, staging 8->4 chunks,
//    LDS 17.4KB) + r25's proven deg*mbp epilogue (k_mbp restored).
//    73 -> ~56us.
// absmax: z f16-rounded per edge (~1-3e-4 expected) - same gamble class
// as r24/r27 which passed. No-spill check: mega WRITE=25.0MB.

typedef _Float16 f16;
typedef _Float16 v8hf __attribute__((ext_vector_type(8)));
typedef _Float16 v2hf __attribute__((ext_vector_type(2)));
typedef float    v16f __attribute__((ext_vector_type(16)));

// WpF segments, each 12 tiles * 8 ks * 512 = 49152 f16:
// seg0: msg_W as B (z = x @ msg_W^T, out cols 0..383)
// seg1: W_ih  (gi = y' @ W_ih^T)
// seg2: W_hh  (gh = x @ W_hh^T)
#define SEGF 49152

__device__ __forceinline__ float sigf(float a){
  return __fdividef(1.0f, 1.0f + __expf(-a));
}
__device__ __forceinline__ float tanhf_fast(float a){
  return 1.0f - __fdividef(2.0f, __expf(2.0f*a) + 1.0f);
}

__global__ void k_diag(float* out, int n, float v){
  int i = threadIdx.x; if(i<n) out[i] = v;
}

__global__ void k_embed(const int* __restrict__ xtype, const int* __restrict__ xtok,
                        const float* __restrict__ xsmall,
                        const float* __restrict__ temb, const float* __restrict__ kemb,
                        f16* __restrict__ xb, int N){
  int n = blockIdx.x; int j = threadIdx.x;
  if(n>=N) return;
  float v;
  if(j<32)       v = temb[xtype[n]*32 + j];
  else if(j<64)  v = kemb[xtok[n]*32 + (j-32)];
  else           v = xsmall[(size_t)n*64 + (j-64)];
  xb[(size_t)n*128 + j] = (f16)v;
}

// Pack weights f16, MFMA B-frag order: n = tile*32+(lane&31), k = ks*16+(lane>>5)*8+j.
// All 3 segs share the [n<384][k<128] form; msg_W flat [t][o][k] == [n*128+k].
__global__ void k_wprep3(const float* __restrict__ msg_W,
                         const float* __restrict__ W_ih,
                         const float* __restrict__ W_hh,
                         f16* __restrict__ WpF){
  int i = blockIdx.x*256 + threadIdx.x;
  if(i >= 3*SEGF) return;
  int seg = i / SEGF;
  int i2 = i % SEGF;
  int grp = i2/512, rem = i2%512;
  int lane = rem/8, j = rem%8;
  int tile = grp/8, ks = grp%8;
  int n = tile*32 + (lane&31);
  int k = ks*16 + (lane>>5)*8 + j;
  const float* W = (seg==0)? msg_W : (seg==1)? W_ih : W_hh;
  WpF[i] = (f16)W[n*128 + k];
}

// mbp[t][o2] = sum_k W_ih[o2,k]*msg_b[t,k]  (restored from r14; feeds the
// deg*mbp gi-epilogue term so gather1/y need not carry msg_b).
__global__ void k_mbp(const float* __restrict__ W_ih, const float* __restrict__ msg_b,
                      float* __restrict__ mbp){
  int i = blockIdx.x*256 + threadIdx.x;
  if(i >= 1152) return;
  int t = i/384, o2 = i%384;
  const float* wr = W_ih + o2*128;
  const float* mb = msg_b + t*128;
  float acc = 0.f;
  #pragma unroll 4
  for(int k2=0;k2<128;k2++) acc += wr[k2]*mb[k2];
  mbp[i] = acc;
}

__global__ void k_hist3(const int* __restrict__ dst, const int* __restrict__ et,
                        int* __restrict__ deg3, int E){
  int e = blockIdx.x*blockDim.x + threadIdx.x;
  if(e<E) atomicAdd(&deg3[dst[e]*3 + et[e]], 1);
}

__global__ void k_scan1(const int* __restrict__ deg, int n, int* __restrict__ part, int* __restrict__ bsum){
  __shared__ int s[256];
  int t = threadIdx.x;
  int base = blockIdx.x*1024 + t*4;
  int v[4]; int sum=0;
  #pragma unroll
  for(int k=0;k<4;k++){ int i=base+k; int d=(i<n)?deg[i]:0; sum+=d; v[k]=sum; }
  s[t]=sum; __syncthreads();
  for(int off=1;off<256;off<<=1){
    int add = (t>=off)? s[t-off] : 0;
    __syncthreads();
    s[t]+=add;
    __syncthreads();
  }
  int excl = (t>0)? s[t-1] : 0;
  #pragma unroll
  for(int k=0;k<4;k++){ int i=base+k; if(i<n) part[i]=v[k]+excl; }
  if(t==255) bsum[blockIdx.x] = s[255];
}

__global__ void k_scan2(const int* __restrict__ bsum, int nb, int* __restrict__ carry){
  if(threadIdx.x==0 && blockIdx.x==0){
    int c=0;
    for(int b=0;b<nb;b++){ carry[b]=c; c+=bsum[b]; }
  }
}

__global__ void k_finalize(const int* __restrict__ part, const int* __restrict__ deg,
                           const int* __restrict__ carry, int n,
                           int* __restrict__ rowptr, int* __restrict__ cursor){
  int i = blockIdx.x*blockDim.x + threadIdx.x;
  if(i>=n) return;
  int incl = part[i] + carry[i>>10];
  rowptr[i+1] = incl;
  cursor[i] = incl - deg[i];
  if(i==0) rowptr[0]=0;
}

// pay stores BYTE offsets into the z table: (et*N + src) * 256.
// Max 3*100000*256 = 76.8M < 2^31.
__global__ void k_fill3(const int* __restrict__ src, const int* __restrict__ dst,
                        const int* __restrict__ et, int* __restrict__ cursor,
                        int* __restrict__ pay, int E, int N){
  int e = blockIdx.x*blockDim.x + threadIdx.x;
  if(e>=E) return;
  int t = et[e];
  int pos = atomicAdd(&cursor[dst[e]*3 + t], 1);
  pay[pos] = (t*N + src[e]) << 8;
}

// Dense per-node transform: z[t][node][128] = xb[node] @ msg_W[t]^T.
// 32 rows/block, 4 waves; wave w -> tiles {w,4+w,8+w} (z cols t*128 + jf).
#define XSTR 136   // 128+8
#define ZSTR 392   // 384+8
__global__ __launch_bounds__(256,3) void k_ztrans(
    const f16* __restrict__ xb, f16* __restrict__ z,
    const f16* __restrict__ WpF, int M, int N)
{
  __shared__ f16 Ax[32*XSTR];   //  8.5 KB
  __shared__ f16 Az[32*ZSTR];   // 24.5 KB
  int tid = threadIdx.x, lane = tid & 63, w = tid >> 6;
  int lrow = lane & 31, q = lane >> 5;
  int row0 = blockIdx.x * 32;

  #pragma unroll
  for(int p=0;p<2;p++){
    int ch = tid + p*256;
    int row = ch>>4, c8 = (ch&15)*8;
    int gr = row0 + row; if(gr >= M) gr = M-1;
    *(v8hf*)&Ax[row*XSTR + c8] = *(const v8hf*)(xb + (size_t)gr*128 + c8);
  }
  __syncthreads();

  v16f a0 = {}, a1 = {}, a2 = {};
  #pragma unroll
  for(int ks=0; ks<8; ks++){
    int kb = ks*16 + q*8;
    v8hf av = *(const v8hf*)&Ax[lrow*XSTR + kb];
    v8hf b0 = *(const v8hf*)(WpF + (size_t)((0*4+w)*8 + ks)*512 + lane*8);
    v8hf b1 = *(const v8hf*)(WpF + (size_t)((1*4+w)*8 + ks)*512 + lane*8);
    v8hf b2 = *(const v8hf*)(WpF + (size_t)((2*4+w)*8 + ks)*512 + lane*8);
    a0 = __builtin_amdgcn_mfma_f32_32x32x16_f16(av, b0, a0, 0,0,0);
    a1 = __builtin_amdgcn_mfma_f32_32x32x16_f16(av, b1, a1, 0,0,0);
    a2 = __builtin_amdgcn_mfma_f32_32x32x16_f16(av, b2, a2, 0,0,0);
  }
  int jf = w*32 + lrow;
  int rq4 = 4*q;
  #pragma unroll
  for(int r=0;r<16;r++){
    int gl = (r&3) + 8*(r>>2) + rq4;
    Az[gl*ZSTR + jf]       = (f16)a0[r];
    Az[gl*ZSTR + 128 + jf] = (f16)a1[r];
    Az[gl*ZSTR + 256 + jf] = (f16)a2[r];
  }
  __syncthreads();
  // coalesced writeback: 1536 chunks, 6/thread; chunk -> z[t][gr][o]
  #pragma unroll
  for(int p=0;p<6;p++){
    int ch = tid + p*256;
    int row = ch/48, cc = (ch%48)*8;
    int gr = row0 + row;
    if(gr < M){
      int t = cc >> 7, o = cc & 127;
      *(v8hf*)(z + ((size_t)t*N + gr)*128 + o) = *(const v8hf*)&Az[row*ZSTR + cc];
    }
  }
}

// gather: 4 nodes per wave (one per 16-lane quarter), lane covers 8 f16
// cols via one v8hf 16B load. Single accumulator (type baked into pay
// offsets) - no bin compares. 3-stream flat split for MLP. f16 packed
// accumulation; write y (128-wide, 25.6MB).
__global__ void k_gather1(const f16* __restrict__ z, const int* __restrict__ rp3,
                          const int* __restrict__ pay, f16* __restrict__ y, int N){
  int tid = threadIdx.x;
  int lane = tid & 63;
  int h = lane >> 4;          // quarter = node select within wave
  int c8b = (lane & 15)*16;   // col byte offset within row
  const char* zb = (const char*)z;
  int n = blockIdx.x*16 + (tid>>6)*4 + h;
  bool valid = (n < N);
  int nn = valid ? n : (N-1);
  int b = nn*3;
  int lo = rp3[b], hi = rp3[b+3];
  if(!valid){ lo = 0; hi = 0; }
  v8hf a = {};
  int len = hi - lo;
  int t1 = lo + len/3;
  int t2 = lo + (2*len)/3;
  int iA = lo, iB = t1, iC = t2;
  while(iA < t1 && iB < t2 && iC < hi){
    int pA = pay[iA], pB = pay[iB], pC = pay[iC];
    v8hf uA = *(const v8hf*)(zb + pA + c8b);
    v8hf uB = *(const v8hf*)(zb + pB + c8b);
    v8hf uC = *(const v8hf*)(zb + pC + c8b);
    a += uA; a += uB; a += uC;
    iA++; iB++; iC++;
  }
  for(; iA < t1; iA++) a += *(const v8hf*)(zb + pay[iA] + c8b);
  for(; iB < t2; iB++) a += *(const v8hf*)(zb + pay[iB] + c8b);
  for(; iC < hi; iC++) a += *(const v8hf*)(zb + pay[iC] + c8b);
  if(valid)
    *(v8hf*)((char*)y + (size_t)n*256 + c8b) = a;
}

// Fused gi+gh GEMM + GRU (stage1 removed). 32 rows/block, 4 waves; wave w
// = feature slice jf in [32w,32w+32), gate tiles {w,4+w,8+w}. r,z gates
// summed (gh continues into acc0/acc1); gi-n packed; gh-n fresh. deg*mbp
// added in epilogue (r25-proven). Peak acc 48 AGPR -> (256,3).
__global__ __launch_bounds__(256,3) void k_mega2t(
    const f16* __restrict__ xb_old, f16* __restrict__ xb_new,
    const f16* __restrict__ y, const f16* __restrict__ WpF,
    const int* __restrict__ deg3, const float* __restrict__ mbp,
    const float* __restrict__ b_ih, const float* __restrict__ b_hh, int M)
{
  __shared__ f16 Ay[32*XSTR];   // 8.5 KB
  __shared__ f16 Ax[32*XSTR];   // 8.5 KB
  __shared__ float Dg[96];
  int tid = threadIdx.x, lane = tid & 63, w = tid >> 6;
  int lrow = lane & 31, q = lane >> 5;
  int row0 = blockIdx.x * 32;

  #pragma unroll
  for(int p=0;p<2;p++){
    int ch = tid + p*256;
    int row = ch>>4, c8 = (ch&15)*8;
    int gr = row0 + row; if(gr >= M) gr = M-1;
    *(v8hf*)&Ax[row*XSTR + c8] = *(const v8hf*)(xb_old + (size_t)gr*128 + c8);
  }
  #pragma unroll
  for(int p=0;p<2;p++){
    int ch = tid + p*256;
    int row = ch>>4, c8 = (ch&15)*8;
    int gr = row0 + row; if(gr >= M) gr = M-1;
    *(v8hf*)&Ay[row*XSTR + c8] = *(const v8hf*)(y + (size_t)gr*128 + c8);
  }
  if(tid < 96){
    int node = row0 + tid/3;
    Dg[tid] = (node < M) ? (float)deg3[node*3 + (tid - (tid/3)*3)] : 0.f;
  }
  __syncthreads();

  int jf = w*32 + lrow;
  int rq4 = 4*q;

  // ---- gi: K=128 over Ay (B seg1); gates r/z/n -> acc0/acc1/acc2 ----
  v16f acc0 = {}, acc1 = {}, acc2 = {};
  #pragma unroll
  for(int ks=0; ks<8; ks++){
    int kb = ks*16 + q*8;
    v8hf a0 = *(const v8hf*)&Ay[lrow*XSTR + kb];
    v8hf b0 = *(const v8hf*)(WpF + SEGF + (size_t)((0*4+w)*8 + ks)*512 + lane*8);
    v8hf b1 = *(const v8hf*)(WpF + SEGF + (size_t)((1*4+w)*8 + ks)*512 + lane*8);
    v8hf b2 = *(const v8hf*)(WpF + SEGF + (size_t)((2*4+w)*8 + ks)*512 + lane*8);
    acc0 = __builtin_amdgcn_mfma_f32_32x32x16_f16(a0, b0, acc0, 0,0,0);
    acc1 = __builtin_amdgcn_mfma_f32_32x32x16_f16(a0, b1, acc1, 0,0,0);
    acc2 = __builtin_amdgcn_mfma_f32_32x32x16_f16(a0, b2, acc2, 0,0,0);
  }
  // pack ONLY gi-n (8 regs); acc2's AGPRs freed for accn
  v2hf gp2[8];
  #pragma unroll
  for(int rp=0; rp<8; rp++){
    v2hf t; t[0] = (f16)acc2[2*rp]; t[1] = (f16)acc2[2*rp+1];
    gp2[rp] = t;
  }

  // ---- gh: K=128 over Ax (B seg2); r,z continue; n fresh ----
  v16f accn = {};
  #pragma unroll
  for(int ks=0; ks<8; ks++){
    int kb = ks*16 + q*8;
    v8hf a0 = *(const v8hf*)&Ax[lrow*XSTR + kb];
    v8hf b0 = *(const v8hf*)(WpF + 2*SEGF + (size_t)((0*4+w)*8 + ks)*512 + lane*8);
    v8hf b1 = *(const v8hf*)(WpF + 2*SEGF + (size_t)((1*4+w)*8 + ks)*512 + lane*8);
    v8hf b2 = *(const v8hf*)(WpF + 2*SEGF + (size_t)((2*4+w)*8 + ks)*512 + lane*8);
    acc0 = __builtin_amdgcn_mfma_f32_32x32x16_f16(a0, b0, acc0, 0,0,0);
    acc1 = __builtin_amdgcn_mfma_f32_32x32x16_f16(a0, b1, acc1, 0,0,0);
    accn = __builtin_amdgcn_mfma_f32_32x32x16_f16(a0, b2, accn, 0,0,0);
  }

  __syncthreads();   // all waves' gh reads of Ax complete before in-place write

  // GRU epilogue; deg*mbp term per gate (r25-proven).
  float br = b_ih[jf]     + b_hh[jf];
  float bz = b_ih[128+jf] + b_hh[128+jf];
  float bi2 = b_ih[256+jf], bh2 = b_hh[256+jf];
  float mb[3][3];
  #pragma unroll
  for(int t=0;t<3;t++){
    mb[t][0] = mbp[t*384 + jf];
    mb[t][1] = mbp[t*384 + 128 + jf];
    mb[t][2] = mbp[t*384 + 256 + jf];
  }
  #pragma unroll
  for(int r=0;r<16;r++){
    int gl = (r&3) + 8*(r>>2) + rq4;
    float d0 = Dg[gl*3], d1 = Dg[gl*3+1], d2 = Dg[gl*3+2];
    float rg = sigf(acc0[r] + br + d0*mb[0][0] + d1*mb[1][0] + d2*mb[2][0]);
    float zg = sigf(acc1[r] + bz + d0*mb[0][1] + d1*mb[1][1] + d2*mb[2][1]);
    float in_ = (float)gp2[r>>1][r&1] + bi2 + d0*mb[0][2] + d1*mb[1][2] + d2*mb[2][2];
    float hn  = accn[r] + bh2;
    float nn = tanhf_fast(in_ + rg*hn);
    float xo = (float)Ax[gl*XSTR + jf];
    Ax[gl*XSTR + jf] = (f16)((1.f - zg)*nn + zg*xo);   // in-place, own slot
  }
  __syncthreads();
  #pragma unroll
  for(int p=0;p<2;p++){
    int ch = tid + p*256;
    int row = ch>>4, c8 = (ch&15)*8;
    int gr = row0 + row;
    if(gr < M)
      *(v8hf*)(xb_new + (size_t)gr*128 + c8) = *(const v8hf*)&Ax[row*XSTR + c8];
  }
}

__device__ __forceinline__ int lb_batch(const int* __restrict__ batch, int N, int g){
  int lo=0, hi=N;
  while(lo<hi){ int mid=(lo+hi)>>1; if(batch[mid]<g) lo=mid+1; else hi=mid; }
  return lo;
}

__global__ void k_pool2(const f16* __restrict__ xb, const int* __restrict__ batch,
                        float* __restrict__ pooled, int N){
  int g = blockIdx.x, slice = blockIdx.y;
  int j = threadIdx.x;
  int lo = lb_batch(batch,N,g), hi = lb_batch(batch,N,g+1);
  float acc = 0.f;
  for(int r=lo+slice; r<hi; r+=32) acc += (float)xb[(size_t)r*128 + j];
  atomicAdd(&pooled[g*128+j], acc);
}

__global__ void k_head(const float* __restrict__ pooled, const int* __restrict__ batch, int N,
                       const float* __restrict__ W1, const float* __restrict__ b1,
                       const float* __restrict__ W2, const float* __restrict__ b2,
                       float* __restrict__ out){
  int g = blockIdx.x; int j = threadIdx.x;
  __shared__ float p[128];
  __shared__ float red[128];
  int lo = lb_batch(batch,N,g), hi = lb_batch(batch,N,g+1);
  float c = (float)(hi-lo); if(c < 1.f) c = 1.f;
  p[j] = pooled[g*128+j] / c;
  __syncthreads();
  float acc = b1[j];
  #pragma unroll 4
  for(int i=0;i<128;i++) acc += W1[j*128+i]*p[i];
  float v = (acc>0.f?acc:0.f) * W2[j];
  red[j] = v; __syncthreads();
  for(int s=64;s>0;s>>=1){ if(j<s) red[j]+=red[j+s]; __syncthreads(); }
  if(j==0) out[g] = red[0] + b2[0];
}

extern "C" void kernel_launch(void* const* d_in, const int* in_sizes, int n_in,
                              void* d_out, int out_size, void* d_ws, size_t ws_size,
                              hipStream_t stream){
  const int*   x_type    = (const int*)d_in[0];
  const int*   x_tok     = (const int*)d_in[1];
  const float* x_small   = (const float*)d_in[2];
  const int*   edge_index= (const int*)d_in[3];
  const int*   edge_type = (const int*)d_in[4];
  const int*   batch     = (const int*)d_in[5];
  const float* type_emb  = (const float*)d_in[6];
  const float* tok_emb   = (const float*)d_in[7];
  const float* msg_W     = (const float*)d_in[8];
  const float* msg_b     = (const float*)d_in[9];
  const float* W_ih      = (const float*)d_in[10];
  const float* W_hh      = (const float*)d_in[11];
  const float* b_ih      = (const float*)d_in[12];
  const float* b_hh      = (const float*)d_in[13];
  const float* pW1       = (const float*)d_in[14];
  const float* pb1       = (const float*)d_in[15];
  const float* pW2       = (const float*)d_in[16];
  const float* pb2       = (const float*)d_in[17];
  float* out = (float*)d_out;

  int N = in_sizes[0];
  int E = in_sizes[3]/2;
  const int* src = edge_index;
  const int* dst = edge_index + E;
  int n3 = 3*N;
  int nch = (n3+1023)/1024;

  char* w = (char*)d_ws;
  size_t off = 0;
  auto alloc = [&](size_t bytes)->char*{ char* p = w + off; off += (bytes + 511) & ~511ull; return p; };
  f16*   xb0    = (f16*)alloc((size_t)N*128*2);       // ping (25.6 MB)
  f16*   xb1    = (f16*)alloc((size_t)N*128*2);       // pong (25.6 MB)
  f16*   z      = (f16*)alloc((size_t)3*N*128*2);     // transformed (76.8 MB)
  f16*   y      = (f16*)alloc((size_t)N*128*2);       // gathered sums (25.6 MB)
  int*   deg3   = (int*)alloc((size_t)n3*4);
  int*   part   = (int*)alloc((size_t)n3*4);
  int*   rp3    = (int*)alloc((size_t)(n3+1)*4);
  int*   cursor = (int*)alloc((size_t)n3*4);
  int*   pay    = (int*)alloc((size_t)E*4);
  int*   bsum   = (int*)alloc((size_t)nch*4);
  int*   carry  = (int*)alloc((size_t)nch*4);
  f16*   WpF    = (f16*)alloc((size_t)(3*SEGF)*2);
  float* mbp    = (float*)alloc((size_t)1152*4);
  float* pooled = (float*)alloc(64*128*4);
  if(off > ws_size){
    k_diag<<<1,64,0,stream>>>(out, out_size, 1.0e6f + (float)(ws_size>>20));
    return;
  }

  const int tb = 256;
  hipMemsetAsync(deg3, 0, (size_t)n3*4, stream);
  k_wprep3  <<<(3*SEGF+255)/256, 256, 0, stream>>>(msg_W, W_ih, W_hh, WpF);
  k_mbp     <<<5, 256, 0, stream>>>(W_ih, msg_b, mbp);
  k_hist3   <<<(E+tb-1)/tb, tb, 0, stream>>>(dst, edge_type, deg3, E);
  k_scan1   <<<nch, 256, 0, stream>>>(deg3, n3, part, bsum);
  k_scan2   <<<1, 64, 0, stream>>>(bsum, nch, carry);
  k_finalize<<<(n3+tb-1)/tb, tb, 0, stream>>>(part, deg3, carry, n3, rp3, cursor);
  k_fill3   <<<(E+tb-1)/tb, tb, 0, stream>>>(src, dst, edge_type, cursor, pay, E, N);
  k_embed   <<<N, 128, 0, stream>>>(x_type, x_tok, x_small, type_emb, tok_emb, xb0, N);

  int nblk = (N+31)/32;
  f16* xin = xb0;
  f16* xout = xb1;
  for(int it=0; it<8; it++){
    k_ztrans <<<nblk, 256, 0, stream>>>(xin, z, WpF, N, N);
    k_gather1<<<(N+15)/16, 256, 0, stream>>>(z, rp3, pay, y, N);
    k_mega2t <<<nblk, 256, 0, stream>>>(xin, xout, y, WpF, deg3, mbp, b_ih, b_hh, N);
    f16* tmp = xin; xin = xout; xout = tmp;
  }
  // final state is in xin after the swap
  hipMemsetAsync(pooled, 0, 64*128*4, stream);
  k_pool2<<<dim3(64,32), 128, 0, stream>>>(xin, batch, pooled, N);
  k_head <<<64, 128, 0, stream>>>(pooled, batch, N, pW1, pb1, pW2, pb2, out);
}